// Round 1
// baseline (1921.359 us; speedup 1.0000x reference)
//
#include <hip/hip_runtime.h>
#include <cstdint>
#include <cstddef>

typedef short bf16x8 __attribute__((ext_vector_type(8)));
typedef float floatx4 __attribute__((ext_vector_type(4)));
typedef unsigned short ushort4v __attribute__((ext_vector_type(4)));

#define LN_EPS 1e-5f
#define ATTN_EPS 1e-8f

__device__ __forceinline__ unsigned short f2bf(float f) {
    unsigned int u = __float_as_uint(f);
    u += 0x7fffu + ((u >> 16) & 1u);
    return (unsigned short)(u >> 16);
}

__device__ __forceinline__ void load_lds16(const void* gp, void* lp) {
    __builtin_amdgcn_global_load_lds(
        (__attribute__((address_space(1))) void*)gp,
        (__attribute__((address_space(3))) void*)lp,
        16, 0, 0);
}

// ---------------- LayerNorm over rows of 512, one wave per row ----------------
template<bool OUT_BF16>
__global__ __launch_bounds__(256) void ln512_kernel(
        const float* __restrict__ x, const float* __restrict__ g, const float* __restrict__ b,
        void* __restrict__ out, int rows, float outscale) {
    int row = blockIdx.x * 4 + (threadIdx.x >> 6);
    int lane = threadIdx.x & 63;
    if (row >= rows) return;
    const float4* xr = (const float4*)(x + (size_t)row * 512);
    float4 a0 = xr[lane];
    float4 a1 = xr[lane + 64];
    float s  = a0.x + a0.y + a0.z + a0.w + a1.x + a1.y + a1.z + a1.w;
    float ss = a0.x*a0.x + a0.y*a0.y + a0.z*a0.z + a0.w*a0.w
             + a1.x*a1.x + a1.y*a1.y + a1.z*a1.z + a1.w*a1.w;
    #pragma unroll
    for (int off = 32; off > 0; off >>= 1) {
        s  += __shfl_xor(s, off, 64);
        ss += __shfl_xor(ss, off, 64);
    }
    float mu = s * (1.0f / 512.0f);
    float var = ss * (1.0f / 512.0f) - mu * mu;
    float rstd = rsqrtf(var + LN_EPS);
    float4 g0 = ((const float4*)g)[lane];
    float4 g1 = ((const float4*)g)[lane + 64];
    float4 b0 = ((const float4*)b)[lane];
    float4 b1 = ((const float4*)b)[lane + 64];
    float y[8];
    y[0] = ((a0.x - mu) * rstd * g0.x + b0.x) * outscale;
    y[1] = ((a0.y - mu) * rstd * g0.y + b0.y) * outscale;
    y[2] = ((a0.z - mu) * rstd * g0.z + b0.z) * outscale;
    y[3] = ((a0.w - mu) * rstd * g0.w + b0.w) * outscale;
    y[4] = ((a1.x - mu) * rstd * g1.x + b1.x) * outscale;
    y[5] = ((a1.y - mu) * rstd * g1.y + b1.y) * outscale;
    y[6] = ((a1.z - mu) * rstd * g1.z + b1.z) * outscale;
    y[7] = ((a1.w - mu) * rstd * g1.w + b1.w) * outscale;
    if (OUT_BF16) {
        unsigned short* orow = (unsigned short*)out + (size_t)row * 512;
        ushort4v o0, o1;
        o0.x = f2bf(y[0]); o0.y = f2bf(y[1]); o0.z = f2bf(y[2]); o0.w = f2bf(y[3]);
        o1.x = f2bf(y[4]); o1.y = f2bf(y[5]); o1.z = f2bf(y[6]); o1.w = f2bf(y[7]);
        *(ushort4v*)(orow + lane * 4) = o0;
        *(ushort4v*)(orow + 256 + lane * 4) = o1;
    } else {
        float* orow = (float*)out + (size_t)row * 512;
        *(float4*)(orow + lane * 4) = make_float4(y[0], y[1], y[2], y[3]);
        *(float4*)(orow + 256 + lane * 4) = make_float4(y[4], y[5], y[6], y[7]);
    }
}

// --------- pack W = [Wk|Wv] transposed to [N=1024][K=512] bf16 ----------
__global__ __launch_bounds__(256) void prep_wt(const float* __restrict__ Wk,
                                               const float* __restrict__ Wv,
                                               unsigned short* __restrict__ wt) {
    int idx = blockIdx.x * 256 + threadIdx.x;  // over 1024*512
    if (idx >= 1024 * 512) return;
    int n = idx >> 9, kk = idx & 511;
    float v = (n < 512) ? Wk[(size_t)kk * 512 + n] : Wv[(size_t)kk * 512 + (n - 512)];
    wt[idx] = f2bf(v);
}

// ---------------- k/v projection GEMM: [131072x512] @ [512x1024] ----------------
// A = xln bf16 row-major [M][512]; B = wt bf16 [N][512] (pre-transposed).
// 128x128 tile, BK=32, 4 waves (2x2 of 64x64), mfma 16x16x32 bf16.
__global__ __launch_bounds__(256) void kv_gemm(
        const unsigned short* __restrict__ xln, const unsigned short* __restrict__ wt,
        const float* __restrict__ bk, const float* __restrict__ bv,
        unsigned short* __restrict__ kout, unsigned short* __restrict__ vout) {
    __shared__ unsigned short As[128 * 32];
    __shared__ unsigned short Bs[128 * 32];
    const int t = threadIdx.x;
    const int lane = t & 63;
    const int w = t >> 6;
    const int wm = w >> 1, wn = w & 1;
    const int m0 = blockIdx.y * 128;
    const int n0 = blockIdx.x * 128;
    const int quad = lane >> 4;
    const int l15 = lane & 15;
    floatx4 acc[4][4];
    #pragma unroll
    for (int i = 0; i < 4; ++i)
        #pragma unroll
        for (int j = 0; j < 4; ++j)
            #pragma unroll
            for (int r = 0; r < 4; ++r) acc[i][j][r] = 0.0f;

    for (int k0 = 0; k0 < 512; k0 += 32) {
        #pragma unroll
        for (int r = 0; r < 2; ++r) {
            const int li = r * 256 + t;
            const int row = li >> 2;
            const int cc = (li & 3) * 8;
            const int ldsoff = (li - lane) * 16;   // bytes; wave-uniform
            load_lds16(xln + (size_t)(m0 + row) * 512 + k0 + cc, (char*)As + ldsoff);
            load_lds16(wt  + (size_t)(n0 + row) * 512 + k0 + cc, (char*)Bs + ldsoff);
        }
        __builtin_amdgcn_s_waitcnt(0);
        __syncthreads();
        bf16x8 af[4], bfr[4];
        #pragma unroll
        for (int i = 0; i < 4; ++i)
            af[i] = *(const bf16x8*)(As + (wm * 64 + i * 16 + l15) * 32 + quad * 8);
        #pragma unroll
        for (int j = 0; j < 4; ++j)
            bfr[j] = *(const bf16x8*)(Bs + (wn * 64 + j * 16 + l15) * 32 + quad * 8);
        #pragma unroll
        for (int i = 0; i < 4; ++i)
            #pragma unroll
            for (int j = 0; j < 4; ++j)
                acc[i][j] = __builtin_amdgcn_mfma_f32_16x16x32_bf16(af[i], bfr[j], acc[i][j], 0, 0, 0);
        __syncthreads();
    }
    #pragma unroll
    for (int j = 0; j < 4; ++j) {
        const int n = n0 + wn * 64 + j * 16 + l15;
        const bool isk = (n < 512);
        const float bias = isk ? bk[n] : bv[n - 512];
        unsigned short* outp = isk ? kout : vout;
        const int nc = isk ? n : n - 512;
        #pragma unroll
        for (int i = 0; i < 4; ++i) {
            #pragma unroll
            for (int r = 0; r < 4; ++r) {
                const int m = m0 + wm * 64 + i * 16 + quad * 4 + r;  // row = quad*4+reg
                outp[(size_t)m * 512 + nc] = f2bf(acc[i][j][r] + bias);
            }
        }
    }
}

// ---------------- fused inverted attention: one streaming pass over k,v ----------------
// grid (16 chunks, 32 batches), block 256 = 4 waves; wave handles 64 n's;
// lane owns d in [lane*8, lane*8+8). Outputs per-(b,chunk) partial U and rowsums.
__global__ __launch_bounds__(256) void attn_kernel(
        const float* __restrict__ q, const unsigned short* __restrict__ kbf,
        const unsigned short* __restrict__ vbf,
        float* __restrict__ Up, float* __restrict__ rsp) {
    const int b = blockIdx.y;
    const int chunk = blockIdx.x;
    const int w = threadIdx.x >> 6, lane = threadIdx.x & 63;
    const int d0 = lane * 8;

    float qr[11][8];
    {
        const float* qb = q + (size_t)b * 11 * 512 + d0;
        #pragma unroll
        for (int s = 0; s < 11; ++s) {
            float4 q0 = *(const float4*)(qb + s * 512);
            float4 q1 = *(const float4*)(qb + s * 512 + 4);
            qr[s][0] = q0.x; qr[s][1] = q0.y; qr[s][2] = q0.z; qr[s][3] = q0.w;
            qr[s][4] = q1.x; qr[s][5] = q1.y; qr[s][6] = q1.z; qr[s][7] = q1.w;
        }
    }
    float U[11][8];
    float rs[11];
    #pragma unroll
    for (int s = 0; s < 11; ++s) {
        rs[s] = 0.f;
        #pragma unroll
        for (int j = 0; j < 8; ++j) U[s][j] = 0.f;
    }

    const size_t base = ((size_t)b * 4096 + (size_t)chunk * 256) * 512 + d0;
    for (int nn = w; nn < 256; nn += 4) {
        const unsigned short* kp = kbf + base + (size_t)nn * 512;
        const unsigned short* vp = vbf + base + (size_t)nn * 512;
        uint4 kr = *(const uint4*)kp;
        float kf[8];
        kf[0] = __uint_as_float(kr.x << 16); kf[1] = __uint_as_float(kr.x & 0xffff0000u);
        kf[2] = __uint_as_float(kr.y << 16); kf[3] = __uint_as_float(kr.y & 0xffff0000u);
        kf[4] = __uint_as_float(kr.z << 16); kf[5] = __uint_as_float(kr.z & 0xffff0000u);
        kf[6] = __uint_as_float(kr.w << 16); kf[7] = __uint_as_float(kr.w & 0xffff0000u);
        float l[11];
        #pragma unroll
        for (int s = 0; s < 11; ++s) {
            float p = kf[0] * qr[s][0];
            #pragma unroll
            for (int j = 1; j < 8; ++j) p = fmaf(kf[j], qr[s][j], p);
            l[s] = p;
        }
        #pragma unroll
        for (int off = 32; off > 0; off >>= 1)
            #pragma unroll
            for (int s = 0; s < 11; ++s) l[s] += __shfl_xor(l[s], off, 64);
        float mx = l[0];
        #pragma unroll
        for (int s = 1; s < 11; ++s) mx = fmaxf(mx, l[s]);
        float se = 0.f;
        #pragma unroll
        for (int s = 0; s < 11; ++s) { l[s] = __expf(l[s] - mx); se += l[s]; }
        float inv = 1.0f / se;
        uint4 vr = *(const uint4*)vp;
        float vf[8];
        vf[0] = __uint_as_float(vr.x << 16); vf[1] = __uint_as_float(vr.x & 0xffff0000u);
        vf[2] = __uint_as_float(vr.y << 16); vf[3] = __uint_as_float(vr.y & 0xffff0000u);
        vf[4] = __uint_as_float(vr.z << 16); vf[5] = __uint_as_float(vr.z & 0xffff0000u);
        vf[6] = __uint_as_float(vr.w << 16); vf[7] = __uint_as_float(vr.w & 0xffff0000u);
        #pragma unroll
        for (int s = 0; s < 11; ++s) {
            float a = l[s] * inv;
            rs[s] += a;
            #pragma unroll
            for (int j = 0; j < 8; ++j) U[s][j] = fmaf(a, vf[j], U[s][j]);
        }
    }
    // block-level reduction across the 4 waves (phased; no atomics)
    __shared__ float Us[11 * 512];
    __shared__ float rss[11];
    for (int ph = 0; ph < 4; ++ph) {
        if (w == ph) {
            #pragma unroll
            for (int s = 0; s < 11; ++s) {
                #pragma unroll
                for (int j = 0; j < 8; ++j) {
                    if (ph == 0) Us[s * 512 + d0 + j] = U[s][j];
                    else         Us[s * 512 + d0 + j] += U[s][j];
                }
            }
            if (lane == 0) {
                #pragma unroll
                for (int s = 0; s < 11; ++s) {
                    if (ph == 0) rss[s] = rs[s]; else rss[s] += rs[s];
                }
            }
        }
        __syncthreads();
    }
    float* up = Up + ((size_t)b * 16 + chunk) * 11 * 512;
    for (int idx = threadIdx.x; idx < 11 * 512; idx += 256) up[idx] = Us[idx];
    if (threadIdx.x < 11) rsp[((size_t)b * 16 + chunk) * 11 + threadIdx.x] = rss[threadIdx.x];
}

// ------------- reduce partials -> updates = U / (rowsum + eps) -------------
__global__ __launch_bounds__(256) void attn_reduce(
        const float* __restrict__ Up, const float* __restrict__ rsp, float* __restrict__ upd) {
    const int bs = blockIdx.x;  // b*11 + s
    const int b = bs / 11, s = bs - b * 11;
    float rsum = ATTN_EPS;
    #pragma unroll
    for (int c = 0; c < 16; ++c) rsum += rsp[((size_t)b * 16 + c) * 11 + s];
    const float inv = 1.0f / rsum;
    for (int d = threadIdx.x; d < 512; d += 256) {
        float acc = 0.f;
        #pragma unroll
        for (int c = 0; c < 16; ++c) acc += Up[(((size_t)b * 16 + c) * 11 + s) * 512 + d];
        upd[((size_t)b * 11 + s) * 512 + d] = acc * inv;
    }
}

// ---------------- small fp32 tiled GEMM: C[M][N] = A[M][K] @ B (+bias,relu) ----------------
// BT=false: B is [K][N]; BT=true: B is [N][K] (i.e. compute A @ B^T).
template<bool BT, bool BIAS, bool RELU>
__global__ __launch_bounds__(256) void sgemm(
        const float* __restrict__ A, const float* __restrict__ Bm,
        const float* __restrict__ bias, float* __restrict__ C,
        int M, int N, int K) {
    __shared__ float Asm[64][33];
    __shared__ float Bsm[32][68];
    const int t = threadIdx.x;
    const int m0 = blockIdx.y * 64, n0 = blockIdx.x * 64;
    const int ty = t >> 4, tx = t & 15;
    float acc[4][4];
    #pragma unroll
    for (int i = 0; i < 4; ++i)
        #pragma unroll
        for (int j = 0; j < 4; ++j) acc[i][j] = 0.f;

    for (int k0 = 0; k0 < K; k0 += 32) {
        #pragma unroll
        for (int p = 0; p < 2; ++p) {
            int row = p * 32 + (t >> 3);
            int c4 = (t & 7) * 4;
            float4 av = make_float4(0.f, 0.f, 0.f, 0.f);
            if (m0 + row < M) av = *(const float4*)(A + (size_t)(m0 + row) * K + k0 + c4);
            Asm[row][c4] = av.x; Asm[row][c4 + 1] = av.y; Asm[row][c4 + 2] = av.z; Asm[row][c4 + 3] = av.w;
        }
        if (!BT) {
            #pragma unroll
            for (int p = 0; p < 2; ++p) {
                int kr = p * 16 + (t >> 4);
                int c4 = (t & 15) * 4;
                float4 bv = *(const float4*)(Bm + (size_t)(k0 + kr) * N + n0 + c4);
                Bsm[kr][c4] = bv.x; Bsm[kr][c4 + 1] = bv.y; Bsm[kr][c4 + 2] = bv.z; Bsm[kr][c4 + 3] = bv.w;
            }
        } else {
            #pragma unroll
            for (int p = 0; p < 2; ++p) {
                int nr = p * 32 + (t >> 3);
                int c4 = (t & 7) * 4;
                float4 bv = *(const float4*)(Bm + (size_t)(n0 + nr) * K + k0 + c4);
                Bsm[c4][nr] = bv.x; Bsm[c4 + 1][nr] = bv.y; Bsm[c4 + 2][nr] = bv.z; Bsm[c4 + 3][nr] = bv.w;
            }
        }
        __syncthreads();
        #pragma unroll
        for (int kk = 0; kk < 32; ++kk) {
            float a4[4];
            #pragma unroll
            for (int i = 0; i < 4; ++i) a4[i] = Asm[ty * 4 + i][kk];
            float4 b4 = *(const float4*)&Bsm[kk][tx * 4];
            #pragma unroll
            for (int i = 0; i < 4; ++i) {
                acc[i][0] = fmaf(a4[i], b4.x, acc[i][0]);
                acc[i][1] = fmaf(a4[i], b4.y, acc[i][1]);
                acc[i][2] = fmaf(a4[i], b4.z, acc[i][2]);
                acc[i][3] = fmaf(a4[i], b4.w, acc[i][3]);
            }
        }
        __syncthreads();
    }
    #pragma unroll
    for (int i = 0; i < 4; ++i) {
        int m = m0 + ty * 4 + i;
        if (m >= M) continue;
        #pragma unroll
        for (int j = 0; j < 4; ++j) {
            int n = n0 + tx * 4 + j;
            float v = acc[i][j];
            if (BIAS) v += bias[n];
            if (RELU) v = fmaxf(v, 0.f);
            C[(size_t)m * N + n] = v;
        }
    }
}

// ---------------- GRU elementwise ----------------
__global__ __launch_bounds__(256) void gru_kernel(
        const float* __restrict__ gi, const float* __restrict__ gh,
        const float* __restrict__ slots, float* __restrict__ out) {
    int idx = blockIdx.x * 256 + threadIdx.x;  // over 352*512
    if (idx >= 352 * 512) return;
    int row = idx >> 9, d = idx & 511;
    const float* gir = gi + (size_t)row * 1536;
    const float* ghr = gh + (size_t)row * 1536;
    float ir = gir[d], iz = gir[512 + d], in_ = gir[1024 + d];
    float hr = ghr[d], hz = ghr[512 + d], hn = ghr[1024 + d];
    float r = 1.f / (1.f + __expf(-(ir + hr)));
    float z = 1.f / (1.f + __expf(-(iz + hz)));
    float n = tanhf(in_ + r * hn);
    out[idx] = (1.f - z) * n + z * slots[idx];
}

extern "C" void kernel_launch(void* const* d_in, const int* in_sizes, int n_in,
                              void* d_out, int out_size, void* d_ws, size_t ws_size,
                              hipStream_t stream) {
    const float* slots_in = (const float*)d_in[0];
    const float* inputs   = (const float*)d_in[1];
    const float* ln_in_g  = (const float*)d_in[2];
    const float* ln_in_b  = (const float*)d_in[3];
    const float* Wk  = (const float*)d_in[4];
    const float* bk  = (const float*)d_in[5];
    const float* Wv  = (const float*)d_in[6];
    const float* bv  = (const float*)d_in[7];
    const float* ln_q_g = (const float*)d_in[8];
    const float* ln_q_b = (const float*)d_in[9];
    const float* Wq  = (const float*)d_in[10];
    const float* W_ih = (const float*)d_in[11];
    const float* b_ih = (const float*)d_in[12];
    const float* W_hh = (const float*)d_in[13];
    const float* b_hh = (const float*)d_in[14];
    const float* ln_m_g = (const float*)d_in[15];
    const float* ln_m_b = (const float*)d_in[16];
    const float* W1 = (const float*)d_in[17];
    const float* b1 = (const float*)d_in[18];
    const float* W2 = (const float*)d_in[19];
    const float* b2 = (const float*)d_in[20];

    char* p = (char*)d_ws;
    auto alloc = [&](size_t bytes) { char* r = p; p += (bytes + 255) & ~(size_t)255; return r; };
    unsigned short* xln = (unsigned short*)alloc(131072ull * 512 * 2);
    unsigned short* wt  = (unsigned short*)alloc(1024ull * 512 * 2);
    unsigned short* kbf = (unsigned short*)alloc(32ull * 4096 * 512 * 2);
    unsigned short* vbf = (unsigned short*)alloc(32ull * 4096 * 512 * 2);
    float* q_    = (float*)alloc(352ull * 512 * 4);
    float* slq   = (float*)alloc(352ull * 512 * 4);
    float* mln   = (float*)alloc(352ull * 512 * 4);
    float* slots = (float*)alloc(352ull * 512 * 4);
    float* upd   = (float*)alloc(352ull * 512 * 4);
    float* gi    = (float*)alloc(352ull * 1536 * 4);
    float* gh    = (float*)alloc(352ull * 1536 * 4);
    float* h1    = (float*)alloc(352ull * 2048 * 4);
    float* Up    = (float*)alloc(32ull * 16 * 11 * 512 * 4);
    float* rsp   = (float*)alloc(32ull * 16 * 11 * 4);

    // one-time: LN(inputs)->bf16, pack weights, k/v projection GEMM
    ln512_kernel<true><<<dim3(32768), 256, 0, stream>>>(inputs, ln_in_g, ln_in_b, xln, 131072, 1.0f);
    prep_wt<<<dim3(2048), 256, 0, stream>>>(Wk, Wv, wt);
    kv_gemm<<<dim3(8, 1024), 256, 0, stream>>>(xln, wt, bk, bv, kbf, vbf);
    hipMemcpyAsync(slots, slots_in, 352ull * 512 * 4, hipMemcpyDeviceToDevice, stream);

    const float qscale = 0.044194173824159216f;  // 1/sqrt(512)
    for (int it = 0; it < 3; ++it) {
        ln512_kernel<false><<<dim3(88), 256, 0, stream>>>(slots, ln_q_g, ln_q_b, slq, 352, qscale);
        sgemm<false, false, false><<<dim3(8, 6), 256, 0, stream>>>(slq, Wq, nullptr, q_, 352, 512, 512);
        attn_kernel<<<dim3(16, 32), 256, 0, stream>>>(q_, kbf, vbf, Up, rsp);
        attn_reduce<<<dim3(352), 256, 0, stream>>>(Up, rsp, upd);
        sgemm<true, true, false><<<dim3(24, 6), 256, 0, stream>>>(upd, W_ih, b_ih, gi, 352, 1536, 512);
        sgemm<true, true, false><<<dim3(24, 6), 256, 0, stream>>>(slots, W_hh, b_hh, gh, 352, 1536, 512);
        gru_kernel<<<dim3(704), 256, 0, stream>>>(gi, gh, slots, slots);
        ln512_kernel<false><<<dim3(88), 256, 0, stream>>>(slots, ln_m_g, ln_m_b, mln, 352, 1.0f);
        sgemm<false, true, true><<<dim3(32, 6), 256, 0, stream>>>(mln, W1, b1, h1, 352, 2048, 512);
        sgemm<false, true, false><<<dim3(8, 6), 256, 0, stream>>>(h1, W2, b2, slots, 352, 512, 2048);
    }
    hipMemcpyAsync(d_out, slots, (size_t)out_size * 4, hipMemcpyDeviceToDevice, stream);
}

// Round 2
// 1343.165 us; speedup vs baseline: 1.4305x; 1.4305x over previous
//
#include <hip/hip_runtime.h>
#include <cstdint>
#include <cstddef>

typedef short bf16x8 __attribute__((ext_vector_type(8)));
typedef float floatx4 __attribute__((ext_vector_type(4)));
typedef unsigned short ushort4v __attribute__((ext_vector_type(4)));

#define LN_EPS 1e-5f
#define ATTN_EPS 1e-8f

__device__ __forceinline__ unsigned short f2bf(float f) {
    unsigned int u = __float_as_uint(f);
    u += 0x7fffu + ((u >> 16) & 1u);
    return (unsigned short)(u >> 16);
}

__device__ __forceinline__ void load_lds16(const void* gp, void* lp) {
    __builtin_amdgcn_global_load_lds(
        (__attribute__((address_space(1))) void*)gp,
        (__attribute__((address_space(3))) void*)lp,
        16, 0, 0);
}

// ---------------- LayerNorm over rows of 512, one wave per row ----------------
// total_rows may exceed data_rows (padding); pad rows duplicate last data row.
template<bool OUT_BF16>
__global__ __launch_bounds__(256) void ln512_kernel(
        const float* __restrict__ x, const float* __restrict__ g, const float* __restrict__ b,
        void* __restrict__ out, int total_rows, int data_rows, float outscale) {
    int row = blockIdx.x * 4 + (threadIdx.x >> 6);
    int lane = threadIdx.x & 63;
    if (row >= total_rows) return;
    int rr = row < data_rows ? row : data_rows - 1;
    const float4* xr = (const float4*)(x + (size_t)rr * 512);
    float4 a0 = xr[lane];
    float4 a1 = xr[lane + 64];
    float s  = a0.x + a0.y + a0.z + a0.w + a1.x + a1.y + a1.z + a1.w;
    float ss = a0.x*a0.x + a0.y*a0.y + a0.z*a0.z + a0.w*a0.w
             + a1.x*a1.x + a1.y*a1.y + a1.z*a1.z + a1.w*a1.w;
    #pragma unroll
    for (int off = 32; off > 0; off >>= 1) {
        s  += __shfl_xor(s, off, 64);
        ss += __shfl_xor(ss, off, 64);
    }
    float mu = s * (1.0f / 512.0f);
    float var = ss * (1.0f / 512.0f) - mu * mu;
    float rstd = rsqrtf(var + LN_EPS);
    float4 g0 = ((const float4*)g)[lane];
    float4 g1 = ((const float4*)g)[lane + 64];
    float4 b0 = ((const float4*)b)[lane];
    float4 b1 = ((const float4*)b)[lane + 64];
    float y[8];
    y[0] = ((a0.x - mu) * rstd * g0.x + b0.x) * outscale;
    y[1] = ((a0.y - mu) * rstd * g0.y + b0.y) * outscale;
    y[2] = ((a0.z - mu) * rstd * g0.z + b0.z) * outscale;
    y[3] = ((a0.w - mu) * rstd * g0.w + b0.w) * outscale;
    y[4] = ((a1.x - mu) * rstd * g1.x + b1.x) * outscale;
    y[5] = ((a1.y - mu) * rstd * g1.y + b1.y) * outscale;
    y[6] = ((a1.z - mu) * rstd * g1.z + b1.z) * outscale;
    y[7] = ((a1.w - mu) * rstd * g1.w + b1.w) * outscale;
    if (OUT_BF16) {
        unsigned short* orow = (unsigned short*)out + (size_t)row * 512;
        ushort4v o0, o1;
        o0.x = f2bf(y[0]); o0.y = f2bf(y[1]); o0.z = f2bf(y[2]); o0.w = f2bf(y[3]);
        o1.x = f2bf(y[4]); o1.y = f2bf(y[5]); o1.z = f2bf(y[6]); o1.w = f2bf(y[7]);
        *(ushort4v*)(orow + lane * 4) = o0;
        *(ushort4v*)(orow + 256 + lane * 4) = o1;
    } else {
        float* orow = (float*)out + (size_t)row * 512;
        *(float4*)(orow + lane * 4) = make_float4(y[0], y[1], y[2], y[3]);
        *(float4*)(orow + 256 + lane * 4) = make_float4(y[4], y[5], y[6], y[7]);
    }
}

// --------- pack W = [Wk|Wv] transposed to [N=1024][K=512] bf16 ----------
__global__ __launch_bounds__(256) void prep_wt(const float* __restrict__ Wk,
                                               const float* __restrict__ Wv,
                                               unsigned short* __restrict__ wt) {
    int idx = blockIdx.x * 256 + threadIdx.x;  // over 1024*512
    if (idx >= 1024 * 512) return;
    int n = idx >> 9, kk = idx & 511;
    float v = (n < 512) ? Wk[(size_t)kk * 512 + n] : Wv[(size_t)kk * 512 + (n - 512)];
    wt[idx] = f2bf(v);
}

// --------- transpose-convert: in [R][C] fp32 -> out [C][R] bf16 ----------
__global__ __launch_bounds__(256) void transpose_bf(const float* __restrict__ in,
                                                    unsigned short* __restrict__ out,
                                                    int R, int C) {
    __shared__ float tile[32][33];
    int bx = blockIdx.x * 32, by = blockIdx.y * 32;
    int tx = threadIdx.x & 31, ty = threadIdx.x >> 5;  // 32x8
    #pragma unroll
    for (int i = 0; i < 32; i += 8)
        tile[ty + i][tx] = in[(size_t)(by + ty + i) * C + bx + tx];
    __syncthreads();
    #pragma unroll
    for (int i = 0; i < 32; i += 8)
        out[(size_t)(bx + ty + i) * R + by + tx] = f2bf(tile[tx][ty + i]);
}

// --------- straight fp32 -> bf16 convert ----------
__global__ __launch_bounds__(256) void conv_bf(const float* __restrict__ in,
                                               unsigned short* __restrict__ out, int n) {
    int i = blockIdx.x * 256 + threadIdx.x;
    if (i < n) out[i] = f2bf(in[i]);
}

// rows-clamped convert: in [data_rows][512] -> out [total][512]
__global__ __launch_bounds__(256) void conv_bf_rows(const float* __restrict__ in,
                                                    unsigned short* __restrict__ out,
                                                    int total, int data_rows) {
    int i = blockIdx.x * 256 + threadIdx.x;
    if (i >= total * 512) return;
    int row = i >> 9, d = i & 511;
    int rr = row < data_rows ? row : data_rows - 1;
    out[i] = f2bf(in[(size_t)rr * 512 + d]);
}

// ---------------- k/v projection GEMM: [131072x512] @ [512x1024] ----------------
__global__ __launch_bounds__(256) void kv_gemm(
        const unsigned short* __restrict__ xln, const unsigned short* __restrict__ wt,
        const float* __restrict__ bk, const float* __restrict__ bv,
        unsigned short* __restrict__ kout, unsigned short* __restrict__ vout) {
    __shared__ unsigned short As[128 * 32];
    __shared__ unsigned short Bs[128 * 32];
    const int t = threadIdx.x;
    const int lane = t & 63;
    const int w = t >> 6;
    const int wm = w >> 1, wn = w & 1;
    const int m0 = blockIdx.y * 128;
    const int n0 = blockIdx.x * 128;
    const int quad = lane >> 4;
    const int l15 = lane & 15;
    floatx4 acc[4][4];
    #pragma unroll
    for (int i = 0; i < 4; ++i)
        #pragma unroll
        for (int j = 0; j < 4; ++j)
            #pragma unroll
            for (int r = 0; r < 4; ++r) acc[i][j][r] = 0.0f;

    for (int k0 = 0; k0 < 512; k0 += 32) {
        #pragma unroll
        for (int r = 0; r < 2; ++r) {
            const int li = r * 256 + t;
            const int row = li >> 2;
            const int cc = (li & 3) * 8;
            const int ldsoff = (li - lane) * 16;   // bytes; wave-uniform
            load_lds16(xln + (size_t)(m0 + row) * 512 + k0 + cc, (char*)As + ldsoff);
            load_lds16(wt  + (size_t)(n0 + row) * 512 + k0 + cc, (char*)Bs + ldsoff);
        }
        __builtin_amdgcn_s_waitcnt(0);
        __syncthreads();
        bf16x8 af[4], bfr[4];
        #pragma unroll
        for (int i = 0; i < 4; ++i)
            af[i] = *(const bf16x8*)(As + (wm * 64 + i * 16 + l15) * 32 + quad * 8);
        #pragma unroll
        for (int j = 0; j < 4; ++j)
            bfr[j] = *(const bf16x8*)(Bs + (wn * 64 + j * 16 + l15) * 32 + quad * 8);
        #pragma unroll
        for (int i = 0; i < 4; ++i)
            #pragma unroll
            for (int j = 0; j < 4; ++j)
                acc[i][j] = __builtin_amdgcn_mfma_f32_16x16x32_bf16(af[i], bfr[j], acc[i][j], 0, 0, 0);
        __syncthreads();
    }
    #pragma unroll
    for (int j = 0; j < 4; ++j) {
        const int n = n0 + wn * 64 + j * 16 + l15;
        const bool isk = (n < 512);
        const float bias = isk ? bk[n] : bv[n - 512];
        unsigned short* outp = isk ? kout : vout;
        const int nc = isk ? n : n - 512;
        #pragma unroll
        for (int i = 0; i < 4; ++i) {
            #pragma unroll
            for (int r = 0; r < 4; ++r) {
                const int m = m0 + wm * 64 + i * 16 + quad * 4 + r;  // row = quad*4+reg
                outp[(size_t)m * 512 + nc] = f2bf(acc[i][j][r] + bias);
            }
        }
    }
}

// ---------------- small bf16 MFMA GEMM: C[M][N] = A[Mpad][K] @ Bt^T ----------------
// A bf16 row-major [>=m_grid*64][K]; Bt bf16 [N][K]. 64x64 tile, 4 waves 2x2.
// OUT_MODE: 0 = fp32 Cf, 1 = bf16 Cb, 2 = both.
template<bool BIAS, bool RELU, int OUT_MODE>
__global__ __launch_bounds__(256) void hgemm(
        const unsigned short* __restrict__ A, const unsigned short* __restrict__ Bt,
        const float* __restrict__ bias, float* __restrict__ Cf,
        unsigned short* __restrict__ Cb, int N, int K) {
    __shared__ unsigned short As[64 * 32];
    __shared__ unsigned short Bs[64 * 32];
    const int t = threadIdx.x;
    const int lane = t & 63;
    const int w = t >> 6;
    const int wm = w >> 1, wn = w & 1;
    const int m0 = blockIdx.y * 64;
    const int n0 = blockIdx.x * 64;
    const int quad = lane >> 4;
    const int l15 = lane & 15;
    floatx4 acc[2][2];
    #pragma unroll
    for (int i = 0; i < 2; ++i)
        #pragma unroll
        for (int j = 0; j < 2; ++j)
            #pragma unroll
            for (int r = 0; r < 4; ++r) acc[i][j][r] = 0.0f;

    const int row = t >> 2;
    const int cc = (t & 3) * 8;
    const int ldsoff = (t - lane) * 16;
    for (int k0 = 0; k0 < K; k0 += 32) {
        load_lds16(A  + (size_t)(m0 + row) * K + k0 + cc, (char*)As + ldsoff);
        load_lds16(Bt + (size_t)(n0 + row) * K + k0 + cc, (char*)Bs + ldsoff);
        __builtin_amdgcn_s_waitcnt(0);
        __syncthreads();
        bf16x8 af[2], bfr[2];
        #pragma unroll
        for (int i = 0; i < 2; ++i)
            af[i] = *(const bf16x8*)(As + (wm * 32 + i * 16 + l15) * 32 + quad * 8);
        #pragma unroll
        for (int j = 0; j < 2; ++j)
            bfr[j] = *(const bf16x8*)(Bs + (wn * 32 + j * 16 + l15) * 32 + quad * 8);
        #pragma unroll
        for (int i = 0; i < 2; ++i)
            #pragma unroll
            for (int j = 0; j < 2; ++j)
                acc[i][j] = __builtin_amdgcn_mfma_f32_16x16x32_bf16(af[i], bfr[j], acc[i][j], 0, 0, 0);
        __syncthreads();
    }
    #pragma unroll
    for (int j = 0; j < 2; ++j) {
        const int n = n0 + wn * 32 + j * 16 + l15;
        const float bb = BIAS ? bias[n] : 0.0f;
        #pragma unroll
        for (int i = 0; i < 2; ++i) {
            #pragma unroll
            for (int r = 0; r < 4; ++r) {
                const int m = m0 + wm * 32 + i * 16 + quad * 4 + r;
                float v = acc[i][j][r] + bb;
                if (RELU) v = fmaxf(v, 0.0f);
                if (OUT_MODE == 0 || OUT_MODE == 2) Cf[(size_t)m * N + n] = v;
                if (OUT_MODE == 1 || OUT_MODE == 2) Cb[(size_t)m * N + n] = f2bf(v);
            }
        }
    }
}

// ---------------- fused inverted attention ----------------
__global__ __launch_bounds__(256) void attn_kernel(
        const float* __restrict__ q, const unsigned short* __restrict__ kbf,
        const unsigned short* __restrict__ vbf,
        float* __restrict__ Up, float* __restrict__ rsp) {
    const int b = blockIdx.y;
    const int chunk = blockIdx.x;
    const int w = threadIdx.x >> 6, lane = threadIdx.x & 63;
    const int d0 = lane * 8;

    float qr[11][8];
    {
        const float* qb = q + (size_t)b * 11 * 512 + d0;
        #pragma unroll
        for (int s = 0; s < 11; ++s) {
            float4 q0 = *(const float4*)(qb + s * 512);
            float4 q1 = *(const float4*)(qb + s * 512 + 4);
            qr[s][0] = q0.x; qr[s][1] = q0.y; qr[s][2] = q0.z; qr[s][3] = q0.w;
            qr[s][4] = q1.x; qr[s][5] = q1.y; qr[s][6] = q1.z; qr[s][7] = q1.w;
        }
    }
    float U[11][8];
    float rs[11];
    #pragma unroll
    for (int s = 0; s < 11; ++s) {
        rs[s] = 0.f;
        #pragma unroll
        for (int j = 0; j < 8; ++j) U[s][j] = 0.f;
    }

    const size_t base = ((size_t)b * 4096 + (size_t)chunk * 256) * 512 + d0;
    for (int nn = w; nn < 256; nn += 4) {
        const unsigned short* kp = kbf + base + (size_t)nn * 512;
        const unsigned short* vp = vbf + base + (size_t)nn * 512;
        uint4 kr = *(const uint4*)kp;
        float kf[8];
        kf[0] = __uint_as_float(kr.x << 16); kf[1] = __uint_as_float(kr.x & 0xffff0000u);
        kf[2] = __uint_as_float(kr.y << 16); kf[3] = __uint_as_float(kr.y & 0xffff0000u);
        kf[4] = __uint_as_float(kr.z << 16); kf[5] = __uint_as_float(kr.z & 0xffff0000u);
        kf[6] = __uint_as_float(kr.w << 16); kf[7] = __uint_as_float(kr.w & 0xffff0000u);
        float l[11];
        #pragma unroll
        for (int s = 0; s < 11; ++s) {
            float p = kf[0] * qr[s][0];
            #pragma unroll
            for (int j = 1; j < 8; ++j) p = fmaf(kf[j], qr[s][j], p);
            l[s] = p;
        }
        #pragma unroll
        for (int off = 32; off > 0; off >>= 1)
            #pragma unroll
            for (int s = 0; s < 11; ++s) l[s] += __shfl_xor(l[s], off, 64);
        float mx = l[0];
        #pragma unroll
        for (int s = 1; s < 11; ++s) mx = fmaxf(mx, l[s]);
        float se = 0.f;
        #pragma unroll
        for (int s = 0; s < 11; ++s) { l[s] = __expf(l[s] - mx); se += l[s]; }
        float inv = 1.0f / se;
        uint4 vr = *(const uint4*)vp;
        float vf[8];
        vf[0] = __uint_as_float(vr.x << 16); vf[1] = __uint_as_float(vr.x & 0xffff0000u);
        vf[2] = __uint_as_float(vr.y << 16); vf[3] = __uint_as_float(vr.y & 0xffff0000u);
        vf[4] = __uint_as_float(vr.z << 16); vf[5] = __uint_as_float(vr.z & 0xffff0000u);
        vf[6] = __uint_as_float(vr.w << 16); vf[7] = __uint_as_float(vr.w & 0xffff0000u);
        #pragma unroll
        for (int s = 0; s < 11; ++s) {
            float a = l[s] * inv;
            rs[s] += a;
            #pragma unroll
            for (int j = 0; j < 8; ++j) U[s][j] = fmaf(a, vf[j], U[s][j]);
        }
    }
    __shared__ float Us[11 * 512];
    __shared__ float rss[11];
    for (int ph = 0; ph < 4; ++ph) {
        if (w == ph) {
            #pragma unroll
            for (int s = 0; s < 11; ++s) {
                #pragma unroll
                for (int j = 0; j < 8; ++j) {
                    if (ph == 0) Us[s * 512 + d0 + j] = U[s][j];
                    else         Us[s * 512 + d0 + j] += U[s][j];
                }
            }
            if (lane == 0) {
                #pragma unroll
                for (int s = 0; s < 11; ++s) {
                    if (ph == 0) rss[s] = rs[s]; else rss[s] += rs[s];
                }
            }
        }
        __syncthreads();
    }
    float* up = Up + ((size_t)b * 16 + chunk) * 11 * 512;
    for (int idx = threadIdx.x; idx < 11 * 512; idx += 256) up[idx] = Us[idx];
    if (threadIdx.x < 11) rsp[((size_t)b * 16 + chunk) * 11 + threadIdx.x] = rss[threadIdx.x];
}

// ------------- reduce partials -> updates(bf16) = U / (rowsum + eps) -------------
__global__ __launch_bounds__(256) void attn_reduce(
        const float* __restrict__ Up, const float* __restrict__ rsp,
        unsigned short* __restrict__ upd) {
    const int bs = blockIdx.x;  // b*11 + s, grid 384 (pad rows -> zeros)
    if (bs >= 352) {
        for (int d = threadIdx.x; d < 512; d += 256) upd[(size_t)bs * 512 + d] = 0;
        return;
    }
    const int b = bs / 11, s = bs - b * 11;
    float rsum = ATTN_EPS;
    #pragma unroll
    for (int c = 0; c < 16; ++c) rsum += rsp[((size_t)b * 16 + c) * 11 + s];
    const float inv = 1.0f / rsum;
    for (int d = threadIdx.x; d < 512; d += 256) {
        float acc = 0.f;
        #pragma unroll
        for (int c = 0; c < 16; ++c) acc += Up[(((size_t)b * 16 + c) * 11 + s) * 512 + d];
        upd[(size_t)bs * 512 + d] = f2bf(acc * inv);
    }
}

// ---------------- GRU elementwise: fp32 out + bf16 mirror ----------------
__global__ __launch_bounds__(256) void gru_kernel(
        const float* __restrict__ gi, const float* __restrict__ gh,
        const float* __restrict__ slots, float* __restrict__ out,
        unsigned short* __restrict__ out_bf) {
    int idx = blockIdx.x * 256 + threadIdx.x;  // over 384*512
    if (idx >= 384 * 512) return;
    int row = idx >> 9, d = idx & 511;
    const float* gir = gi + (size_t)row * 1536;
    const float* ghr = gh + (size_t)row * 1536;
    float ir = gir[d], iz = gir[512 + d], in_ = gir[1024 + d];
    float hr = ghr[d], hz = ghr[512 + d], hn = ghr[1024 + d];
    float r = 1.f / (1.f + __expf(-(ir + hr)));
    float z = 1.f / (1.f + __expf(-(iz + hz)));
    float n = tanhf(in_ + r * hn);
    float v = (1.f - z) * n + z * slots[idx];
    out[idx] = v;
    out_bf[idx] = f2bf(v);
}

extern "C" void kernel_launch(void* const* d_in, const int* in_sizes, int n_in,
                              void* d_out, int out_size, void* d_ws, size_t ws_size,
                              hipStream_t stream) {
    const float* slots_in = (const float*)d_in[0];
    const float* inputs   = (const float*)d_in[1];
    const float* ln_in_g  = (const float*)d_in[2];
    const float* ln_in_b  = (const float*)d_in[3];
    const float* Wk  = (const float*)d_in[4];
    const float* bk  = (const float*)d_in[5];
    const float* Wv  = (const float*)d_in[6];
    const float* bv  = (const float*)d_in[7];
    const float* ln_q_g = (const float*)d_in[8];
    const float* ln_q_b = (const float*)d_in[9];
    const float* Wq  = (const float*)d_in[10];
    const float* W_ih = (const float*)d_in[11];
    const float* b_ih = (const float*)d_in[12];
    const float* W_hh = (const float*)d_in[13];
    const float* b_hh = (const float*)d_in[14];
    const float* ln_m_g = (const float*)d_in[15];
    const float* ln_m_b = (const float*)d_in[16];
    const float* W1 = (const float*)d_in[17];
    const float* b1 = (const float*)d_in[18];
    const float* W2 = (const float*)d_in[19];
    const float* b2 = (const float*)d_in[20];

    char* p = (char*)d_ws;
    auto alloc = [&](size_t bytes) { char* r = p; p += (bytes + 255) & ~(size_t)255; return r; };
    unsigned short* xln = (unsigned short*)alloc(131072ull * 512 * 2);
    unsigned short* wt  = (unsigned short*)alloc(1024ull * 512 * 2);
    unsigned short* kbf = (unsigned short*)alloc(32ull * 4096 * 512 * 2);
    unsigned short* vbf = (unsigned short*)alloc(32ull * 4096 * 512 * 2);
    // bf16 weights for per-iter GEMMs
    unsigned short* WqT   = (unsigned short*)alloc(512ull * 512 * 2);   // [N=512][K=512]
    unsigned short* Wih_b = (unsigned short*)alloc(1536ull * 512 * 2);  // [1536][512]
    unsigned short* Whh_b = (unsigned short*)alloc(1536ull * 512 * 2);
    unsigned short* W1T   = (unsigned short*)alloc(2048ull * 512 * 2);  // [2048][512]
    unsigned short* W2T   = (unsigned short*)alloc(512ull * 2048 * 2);  // [512][2048]
    // activations (384-row padded)
    unsigned short* slq  = (unsigned short*)alloc(384ull * 512 * 2);
    unsigned short* mln  = (unsigned short*)alloc(384ull * 512 * 2);
    unsigned short* upd  = (unsigned short*)alloc(384ull * 512 * 2);
    unsigned short* slbf = (unsigned short*)alloc(384ull * 512 * 2);
    unsigned short* h1   = (unsigned short*)alloc(384ull * 2048 * 2);
    float* q_    = (float*)alloc(384ull * 512 * 4);
    float* slots = (float*)alloc(384ull * 512 * 4);
    float* gi    = (float*)alloc(384ull * 1536 * 4);
    float* gh    = (float*)alloc(384ull * 1536 * 4);
    float* Up    = (float*)alloc(32ull * 16 * 11 * 512 * 4);
    float* rsp   = (float*)alloc(32ull * 16 * 11 * 4);

    // ---- one-time prep ----
    ln512_kernel<true><<<dim3(32768), 256, 0, stream>>>(inputs, ln_in_g, ln_in_b, xln, 131072, 131072, 1.0f);
    prep_wt<<<dim3(2048), 256, 0, stream>>>(Wk, Wv, wt);
    transpose_bf<<<dim3(16, 16), 256, 0, stream>>>(Wq, WqT, 512, 512);     // [512][512] -> [512][512]^T
    conv_bf<<<dim3(3072), 256, 0, stream>>>(W_ih, Wih_b, 1536 * 512);
    conv_bf<<<dim3(3072), 256, 0, stream>>>(W_hh, Whh_b, 1536 * 512);
    transpose_bf<<<dim3(64, 16), 256, 0, stream>>>(W1, W1T, 512, 2048);    // [512][2048] -> [2048][512]
    transpose_bf<<<dim3(16, 64), 256, 0, stream>>>(W2, W2T, 2048, 512);    // [2048][512] -> [512][2048]
    kv_gemm<<<dim3(8, 1024), 256, 0, stream>>>(xln, wt, bk, bv, kbf, vbf);
    hipMemcpyAsync(slots, slots_in, 352ull * 512 * 4, hipMemcpyDeviceToDevice, stream);
    conv_bf_rows<<<dim3(768), 256, 0, stream>>>(slots_in, slbf, 384, 352);

    const float qscale = 0.044194173824159216f;  // 1/sqrt(512)
    for (int it = 0; it < 3; ++it) {
        ln512_kernel<true><<<dim3(96), 256, 0, stream>>>(slots, ln_q_g, ln_q_b, slq, 384, 352, qscale);
        hgemm<false, false, 0><<<dim3(8, 6), 256, 0, stream>>>(slq, WqT, nullptr, q_, nullptr, 512, 512);
        attn_kernel<<<dim3(16, 32), 256, 0, stream>>>(q_, kbf, vbf, Up, rsp);
        attn_reduce<<<dim3(384), 256, 0, stream>>>(Up, rsp, upd);
        hgemm<true, false, 0><<<dim3(24, 6), 256, 0, stream>>>(upd, Wih_b, b_ih, gi, nullptr, 1536, 512);
        hgemm<true, false, 0><<<dim3(24, 6), 256, 0, stream>>>(slbf, Whh_b, b_hh, gh, nullptr, 1536, 512);
        gru_kernel<<<dim3(768), 256, 0, stream>>>(gi, gh, slots, slots, slbf);
        ln512_kernel<true><<<dim3(96), 256, 0, stream>>>(slots, ln_m_g, ln_m_b, mln, 384, 352, 1.0f);
        hgemm<true, true, 1><<<dim3(32, 6), 256, 0, stream>>>(mln, W1T, b1, nullptr, h1, 2048, 512);
        hgemm<true, false, 2><<<dim3(8, 6), 256, 0, stream>>>(h1, W2T, b2, slots, slbf, 512, 2048);
    }
    hipMemcpyAsync(d_out, slots, (size_t)out_size * 4, hipMemcpyDeviceToDevice, stream);
}

// Round 3
// 1330.529 us; speedup vs baseline: 1.4441x; 1.0095x over previous
//
#include <hip/hip_runtime.h>
#include <cstdint>
#include <cstddef>

typedef short bf16x8 __attribute__((ext_vector_type(8)));
typedef float floatx4 __attribute__((ext_vector_type(4)));
typedef unsigned short ushort4v __attribute__((ext_vector_type(4)));

#define LN_EPS 1e-5f
#define ATTN_EPS 1e-8f
#define NCHUNK 32

__device__ __forceinline__ unsigned short f2bf(float f) {
    unsigned int u = __float_as_uint(f);
    u += 0x7fffu + ((u >> 16) & 1u);
    return (unsigned short)(u >> 16);
}

__device__ __forceinline__ void load_lds16(const void* gp, void* lp) {
    __builtin_amdgcn_global_load_lds(
        (__attribute__((address_space(1))) void*)gp,
        (__attribute__((address_space(3))) void*)lp,
        16, 0, 0);
}

// ---------------- LayerNorm over rows of 512, one wave per row ----------------
template<bool OUT_BF16>
__global__ __launch_bounds__(256) void ln512_kernel(
        const float* __restrict__ x, const float* __restrict__ g, const float* __restrict__ b,
        void* __restrict__ out, int total_rows, int data_rows, float outscale) {
    int row = blockIdx.x * 4 + (threadIdx.x >> 6);
    int lane = threadIdx.x & 63;
    if (row >= total_rows) return;
    int rr = row < data_rows ? row : data_rows - 1;
    const float4* xr = (const float4*)(x + (size_t)rr * 512);
    float4 a0 = xr[lane];
    float4 a1 = xr[lane + 64];
    float s  = a0.x + a0.y + a0.z + a0.w + a1.x + a1.y + a1.z + a1.w;
    float ss = a0.x*a0.x + a0.y*a0.y + a0.z*a0.z + a0.w*a0.w
             + a1.x*a1.x + a1.y*a1.y + a1.z*a1.z + a1.w*a1.w;
    #pragma unroll
    for (int off = 32; off > 0; off >>= 1) {
        s  += __shfl_xor(s, off, 64);
        ss += __shfl_xor(ss, off, 64);
    }
    float mu = s * (1.0f / 512.0f);
    float var = ss * (1.0f / 512.0f) - mu * mu;
    float rstd = rsqrtf(var + LN_EPS);
    float4 g0 = ((const float4*)g)[lane];
    float4 g1 = ((const float4*)g)[lane + 64];
    float4 b0 = ((const float4*)b)[lane];
    float4 b1 = ((const float4*)b)[lane + 64];
    float y[8];
    y[0] = ((a0.x - mu) * rstd * g0.x + b0.x) * outscale;
    y[1] = ((a0.y - mu) * rstd * g0.y + b0.y) * outscale;
    y[2] = ((a0.z - mu) * rstd * g0.z + b0.z) * outscale;
    y[3] = ((a0.w - mu) * rstd * g0.w + b0.w) * outscale;
    y[4] = ((a1.x - mu) * rstd * g1.x + b1.x) * outscale;
    y[5] = ((a1.y - mu) * rstd * g1.y + b1.y) * outscale;
    y[6] = ((a1.z - mu) * rstd * g1.z + b1.z) * outscale;
    y[7] = ((a1.w - mu) * rstd * g1.w + b1.w) * outscale;
    if (OUT_BF16) {
        unsigned short* orow = (unsigned short*)out + (size_t)row * 512;
        ushort4v o0, o1;
        o0.x = f2bf(y[0]); o0.y = f2bf(y[1]); o0.z = f2bf(y[2]); o0.w = f2bf(y[3]);
        o1.x = f2bf(y[4]); o1.y = f2bf(y[5]); o1.z = f2bf(y[6]); o1.w = f2bf(y[7]);
        *(ushort4v*)(orow + lane * 4) = o0;
        *(ushort4v*)(orow + 256 + lane * 4) = o1;
    } else {
        float* orow = (float*)out + (size_t)row * 512;
        *(float4*)(orow + lane * 4) = make_float4(y[0], y[1], y[2], y[3]);
        *(float4*)(orow + 256 + lane * 4) = make_float4(y[4], y[5], y[6], y[7]);
    }
}

// --------- pack W = [Wk|Wv] transposed to [N=1024][K=512] bf16 ----------
__global__ __launch_bounds__(256) void prep_wt(const float* __restrict__ Wk,
                                               const float* __restrict__ Wv,
                                               unsigned short* __restrict__ wt) {
    int idx = blockIdx.x * 256 + threadIdx.x;
    if (idx >= 1024 * 512) return;
    int n = idx >> 9, kk = idx & 511;
    float v = (n < 512) ? Wk[(size_t)kk * 512 + n] : Wv[(size_t)kk * 512 + (n - 512)];
    wt[idx] = f2bf(v);
}

// --------- transpose-convert: in [R][C] fp32 -> out [C][R] bf16 ----------
__global__ __launch_bounds__(256) void transpose_bf(const float* __restrict__ in,
                                                    unsigned short* __restrict__ out,
                                                    int R, int C) {
    __shared__ float tile[32][33];
    int bx = blockIdx.x * 32, by = blockIdx.y * 32;
    int tx = threadIdx.x & 31, ty = threadIdx.x >> 5;
    #pragma unroll
    for (int i = 0; i < 32; i += 8)
        tile[ty + i][tx] = in[(size_t)(by + ty + i) * C + bx + tx];
    __syncthreads();
    #pragma unroll
    for (int i = 0; i < 32; i += 8)
        out[(size_t)(bx + ty + i) * R + by + tx] = f2bf(tile[tx][ty + i]);
}

__global__ __launch_bounds__(256) void conv_bf(const float* __restrict__ in,
                                               unsigned short* __restrict__ out, int n) {
    int i = blockIdx.x * 256 + threadIdx.x;
    if (i < n) out[i] = f2bf(in[i]);
}

__global__ __launch_bounds__(256) void conv_bf_rows(const float* __restrict__ in,
                                                    unsigned short* __restrict__ out,
                                                    int total, int data_rows) {
    int i = blockIdx.x * 256 + threadIdx.x;
    if (i >= total * 512) return;
    int row = i >> 9, d = i & 511;
    int rr = row < data_rows ? row : data_rows - 1;
    out[i] = f2bf(in[(size_t)rr * 512 + d]);
}

// ---------------- k/v projection GEMM: [131072x512] @ [512x1024] ----------------
// 128x128 tile, BK=64, XOR-swizzled LDS chunks (2-way max bank alias),
// XCD-stripe grid swizzle for L2 A-reuse.
__global__ __launch_bounds__(256) void kv_gemm(
        const unsigned short* __restrict__ xln, const unsigned short* __restrict__ wt,
        const float* __restrict__ bk, const float* __restrict__ bv,
        unsigned short* __restrict__ kout, unsigned short* __restrict__ vout) {
    __shared__ unsigned short As[128 * 64];
    __shared__ unsigned short Bs[128 * 64];
    const int t = threadIdx.x;
    const int lane = t & 63;
    const int w = t >> 6;
    const int wm = w >> 1, wn = w & 1;
    // XCD-stripe swizzle: xcd = id%8 gets m-blocks {k*8+xcd}, sweeping n within
    const int id = blockIdx.x;
    const int xcd = id & 7;
    const int slot = id >> 3;
    const int n0 = (slot & 7) * 128;
    const int m0 = (((slot >> 3) << 3) | xcd) * 128;
    const int quad = lane >> 4;
    const int l15 = lane & 15;
    floatx4 acc[4][4];
    #pragma unroll
    for (int i = 0; i < 4; ++i)
        #pragma unroll
        for (int j = 0; j < 4; ++j)
            #pragma unroll
            for (int r = 0; r < 4; ++r) acc[i][j][r] = 0.0f;

    for (int k0 = 0; k0 < 512; k0 += 64) {
        #pragma unroll
        for (int p = 0; p < 4; ++p) {
            const int s = p * 256 + t;          // LDS slot (16B units)
            const int row = s >> 3;
            const int c = (s & 7) ^ (row & 7);  // swizzled source chunk
            const int ldsoff = (s - lane) * 16; // wave-uniform base
            load_lds16(xln + (size_t)(m0 + row) * 512 + k0 + c * 8, (char*)As + ldsoff);
            load_lds16(wt  + (size_t)(n0 + row) * 512 + k0 + c * 8, (char*)Bs + ldsoff);
        }
        __builtin_amdgcn_s_waitcnt(0);
        __syncthreads();
        #pragma unroll
        for (int h = 0; h < 2; ++h) {
            bf16x8 af[4], bfr[4];
            #pragma unroll
            for (int i = 0; i < 4; ++i) {
                const int row = wm * 64 + i * 16 + l15;
                const int cp = ((h << 2) | quad) ^ (l15 & 7);
                af[i] = *(const bf16x8*)(As + row * 64 + cp * 8);
            }
            #pragma unroll
            for (int j = 0; j < 4; ++j) {
                const int row = wn * 64 + j * 16 + l15;
                const int cp = ((h << 2) | quad) ^ (l15 & 7);
                bfr[j] = *(const bf16x8*)(Bs + row * 64 + cp * 8);
            }
            #pragma unroll
            for (int i = 0; i < 4; ++i)
                #pragma unroll
                for (int j = 0; j < 4; ++j)
                    acc[i][j] = __builtin_amdgcn_mfma_f32_16x16x32_bf16(af[i], bfr[j], acc[i][j], 0, 0, 0);
        }
        __syncthreads();
    }
    #pragma unroll
    for (int j = 0; j < 4; ++j) {
        const int n = (slot & 7) * 128 + wn * 64 + j * 16 + l15;
        const bool isk = (n < 512);
        const float bias = isk ? bk[n] : bv[n - 512];
        unsigned short* outp = isk ? kout : vout;
        const int nc = isk ? n : n - 512;
        #pragma unroll
        for (int i = 0; i < 4; ++i) {
            #pragma unroll
            for (int r = 0; r < 4; ++r) {
                const int m = m0 + wm * 64 + i * 16 + quad * 4 + r;
                outp[(size_t)m * 512 + nc] = f2bf(acc[i][j][r] + bias);
            }
        }
    }
}

// ---------------- small bf16 MFMA GEMM: 64x64 tile, BK=64, swizzled LDS ----------------
// OUT_MODE: 0 = fp32 Cf, 1 = bf16 Cb, 2 = both.
template<bool BIAS, bool RELU, int OUT_MODE>
__global__ __launch_bounds__(256) void hgemm(
        const unsigned short* __restrict__ A, const unsigned short* __restrict__ Bt,
        const float* __restrict__ bias, float* __restrict__ Cf,
        unsigned short* __restrict__ Cb, int N, int K) {
    __shared__ unsigned short As[64 * 64];
    __shared__ unsigned short Bs[64 * 64];
    const int t = threadIdx.x;
    const int lane = t & 63;
    const int w = t >> 6;
    const int wm = w >> 1, wn = w & 1;
    const int m0 = blockIdx.y * 64;
    const int n0 = blockIdx.x * 64;
    const int quad = lane >> 4;
    const int l15 = lane & 15;
    floatx4 acc[2][2];
    #pragma unroll
    for (int i = 0; i < 2; ++i)
        #pragma unroll
        for (int j = 0; j < 2; ++j)
            #pragma unroll
            for (int r = 0; r < 4; ++r) acc[i][j][r] = 0.0f;

    for (int k0 = 0; k0 < K; k0 += 64) {
        #pragma unroll
        for (int p = 0; p < 2; ++p) {
            const int s = p * 256 + t;
            const int row = s >> 3;
            const int c = (s & 7) ^ (row & 7);
            const int ldsoff = (s - lane) * 16;
            load_lds16(A  + (size_t)(m0 + row) * K + k0 + c * 8, (char*)As + ldsoff);
            load_lds16(Bt + (size_t)(n0 + row) * K + k0 + c * 8, (char*)Bs + ldsoff);
        }
        __builtin_amdgcn_s_waitcnt(0);
        __syncthreads();
        #pragma unroll
        for (int h = 0; h < 2; ++h) {
            bf16x8 af[2], bfr[2];
            #pragma unroll
            for (int i = 0; i < 2; ++i) {
                const int row = wm * 32 + i * 16 + l15;
                const int cp = ((h << 2) | quad) ^ (l15 & 7);
                af[i] = *(const bf16x8*)(As + row * 64 + cp * 8);
            }
            #pragma unroll
            for (int j = 0; j < 2; ++j) {
                const int row = wn * 32 + j * 16 + l15;
                const int cp = ((h << 2) | quad) ^ (l15 & 7);
                bfr[j] = *(const bf16x8*)(Bs + row * 64 + cp * 8);
            }
            #pragma unroll
            for (int i = 0; i < 2; ++i)
                #pragma unroll
                for (int j = 0; j < 2; ++j)
                    acc[i][j] = __builtin_amdgcn_mfma_f32_16x16x32_bf16(af[i], bfr[j], acc[i][j], 0, 0, 0);
        }
        __syncthreads();
    }
    #pragma unroll
    for (int j = 0; j < 2; ++j) {
        const int n = n0 + wn * 32 + j * 16 + l15;
        const float bb = BIAS ? bias[n] : 0.0f;
        #pragma unroll
        for (int i = 0; i < 2; ++i) {
            #pragma unroll
            for (int r = 0; r < 4; ++r) {
                const int m = m0 + wm * 32 + i * 16 + quad * 4 + r;
                float v = acc[i][j][r] + bb;
                if (RELU) v = fmaxf(v, 0.0f);
                if (OUT_MODE == 0 || OUT_MODE == 2) Cf[(size_t)m * N + n] = v;
                if (OUT_MODE == 1 || OUT_MODE == 2) Cb[(size_t)m * N + n] = f2bf(v);
            }
        }
    }
}

// ---------------- fused inverted attention ----------------
__global__ __launch_bounds__(256) void attn_kernel(
        const float* __restrict__ q, const unsigned short* __restrict__ kbf,
        const unsigned short* __restrict__ vbf,
        float* __restrict__ Up, float* __restrict__ rsp) {
    const int b = blockIdx.y;
    const int chunk = blockIdx.x;
    const int w = threadIdx.x >> 6, lane = threadIdx.x & 63;
    const int d0 = lane * 8;
    const int NPC = 4096 / NCHUNK;

    float qr[11][8];
    {
        const float* qb = q + (size_t)b * 11 * 512 + d0;
        #pragma unroll
        for (int s = 0; s < 11; ++s) {
            float4 q0 = *(const float4*)(qb + s * 512);
            float4 q1 = *(const float4*)(qb + s * 512 + 4);
            qr[s][0] = q0.x; qr[s][1] = q0.y; qr[s][2] = q0.z; qr[s][3] = q0.w;
            qr[s][4] = q1.x; qr[s][5] = q1.y; qr[s][6] = q1.z; qr[s][7] = q1.w;
        }
    }
    float U[11][8];
    float rs[11];
    #pragma unroll
    for (int s = 0; s < 11; ++s) {
        rs[s] = 0.f;
        #pragma unroll
        for (int j = 0; j < 8; ++j) U[s][j] = 0.f;
    }

    const size_t base = ((size_t)b * 4096 + (size_t)chunk * NPC) * 512 + d0;
    for (int nn = w; nn < NPC; nn += 4) {
        const unsigned short* kp = kbf + base + (size_t)nn * 512;
        const unsigned short* vp = vbf + base + (size_t)nn * 512;
        uint4 kr = *(const uint4*)kp;
        float kf[8];
        kf[0] = __uint_as_float(kr.x << 16); kf[1] = __uint_as_float(kr.x & 0xffff0000u);
        kf[2] = __uint_as_float(kr.y << 16); kf[3] = __uint_as_float(kr.y & 0xffff0000u);
        kf[4] = __uint_as_float(kr.z << 16); kf[5] = __uint_as_float(kr.z & 0xffff0000u);
        kf[6] = __uint_as_float(kr.w << 16); kf[7] = __uint_as_float(kr.w & 0xffff0000u);
        float l[11];
        #pragma unroll
        for (int s = 0; s < 11; ++s) {
            float p = kf[0] * qr[s][0];
            #pragma unroll
            for (int j = 1; j < 8; ++j) p = fmaf(kf[j], qr[s][j], p);
            l[s] = p;
        }
        #pragma unroll
        for (int off = 32; off > 0; off >>= 1)
            #pragma unroll
            for (int s = 0; s < 11; ++s) l[s] += __shfl_xor(l[s], off, 64);
        float mx = l[0];
        #pragma unroll
        for (int s = 1; s < 11; ++s) mx = fmaxf(mx, l[s]);
        float se = 0.f;
        #pragma unroll
        for (int s = 0; s < 11; ++s) { l[s] = __expf(l[s] - mx); se += l[s]; }
        float inv = 1.0f / se;
        uint4 vr = *(const uint4*)vp;
        float vf[8];
        vf[0] = __uint_as_float(vr.x << 16); vf[1] = __uint_as_float(vr.x & 0xffff0000u);
        vf[2] = __uint_as_float(vr.y << 16); vf[3] = __uint_as_float(vr.y & 0xffff0000u);
        vf[4] = __uint_as_float(vr.z << 16); vf[5] = __uint_as_float(vr.z & 0xffff0000u);
        vf[6] = __uint_as_float(vr.w << 16); vf[7] = __uint_as_float(vr.w & 0xffff0000u);
        #pragma unroll
        for (int s = 0; s < 11; ++s) {
            float a = l[s] * inv;
            rs[s] += a;
            #pragma unroll
            for (int j = 0; j < 8; ++j) U[s][j] = fmaf(a, vf[j], U[s][j]);
        }
    }
    __shared__ float Us[11 * 512];
    __shared__ float rss[11];
    for (int ph = 0; ph < 4; ++ph) {
        if (w == ph) {
            #pragma unroll
            for (int s = 0; s < 11; ++s) {
                #pragma unroll
                for (int j = 0; j < 8; ++j) {
                    if (ph == 0) Us[s * 512 + d0 + j] = U[s][j];
                    else         Us[s * 512 + d0 + j] += U[s][j];
                }
            }
            if (lane == 0) {
                #pragma unroll
                for (int s = 0; s < 11; ++s) {
                    if (ph == 0) rss[s] = rs[s]; else rss[s] += rs[s];
                }
            }
        }
        __syncthreads();
    }
    float* up = Up + ((size_t)b * NCHUNK + chunk) * 11 * 512;
    for (int idx = threadIdx.x; idx < 11 * 512; idx += 256) up[idx] = Us[idx];
    if (threadIdx.x < 11) rsp[((size_t)b * NCHUNK + chunk) * 11 + threadIdx.x] = rss[threadIdx.x];
}

// ------------- reduce partials -> updates(bf16) = U / (rowsum + eps) -------------
__global__ __launch_bounds__(256) void attn_reduce(
        const float* __restrict__ Up, const float* __restrict__ rsp,
        unsigned short* __restrict__ upd) {
    const int bs = blockIdx.x;  // grid 384 (pad rows -> zeros)
    if (bs >= 352) {
        for (int d = threadIdx.x; d < 512; d += 256) upd[(size_t)bs * 512 + d] = 0;
        return;
    }
    const int b = bs / 11, s = bs - b * 11;
    float rsum = ATTN_EPS;
    #pragma unroll
    for (int c = 0; c < NCHUNK; ++c) rsum += rsp[((size_t)b * NCHUNK + c) * 11 + s];
    const float inv = 1.0f / rsum;
    for (int d = threadIdx.x; d < 512; d += 256) {
        float acc = 0.f;
        #pragma unroll
        for (int c = 0; c < NCHUNK; ++c) acc += Up[(((size_t)b * NCHUNK + c) * 11 + s) * 512 + d];
        upd[(size_t)bs * 512 + d] = f2bf(acc * inv);
    }
}

// ---------------- GRU elementwise: fp32 out + bf16 mirror ----------------
__global__ __launch_bounds__(256) void gru_kernel(
        const float* __restrict__ gi, const float* __restrict__ gh,
        const float* __restrict__ slots, float* __restrict__ out,
        unsigned short* __restrict__ out_bf) {
    int idx = blockIdx.x * 256 + threadIdx.x;
    if (idx >= 384 * 512) return;
    int row = idx >> 9, d = idx & 511;
    const float* gir = gi + (size_t)row * 1536;
    const float* ghr = gh + (size_t)row * 1536;
    float ir = gir[d], iz = gir[512 + d], in_ = gir[1024 + d];
    float hr = ghr[d], hz = ghr[512 + d], hn = ghr[1024 + d];
    float r = 1.f / (1.f + __expf(-(ir + hr)));
    float z = 1.f / (1.f + __expf(-(iz + hz)));
    float n = tanhf(in_ + r * hn);
    float v = (1.f - z) * n + z * slots[idx];
    out[idx] = v;
    out_bf[idx] = f2bf(v);
}

extern "C" void kernel_launch(void* const* d_in, const int* in_sizes, int n_in,
                              void* d_out, int out_size, void* d_ws, size_t ws_size,
                              hipStream_t stream) {
    const float* slots_in = (const float*)d_in[0];
    const float* inputs   = (const float*)d_in[1];
    const float* ln_in_g  = (const float*)d_in[2];
    const float* ln_in_b  = (const float*)d_in[3];
    const float* Wk  = (const float*)d_in[4];
    const float* bk  = (const float*)d_in[5];
    const float* Wv  = (const float*)d_in[6];
    const float* bv  = (const float*)d_in[7];
    const float* ln_q_g = (const float*)d_in[8];
    const float* ln_q_b = (const float*)d_in[9];
    const float* Wq  = (const float*)d_in[10];
    const float* W_ih = (const float*)d_in[11];
    const float* b_ih = (const float*)d_in[12];
    const float* W_hh = (const float*)d_in[13];
    const float* b_hh = (const float*)d_in[14];
    const float* ln_m_g = (const float*)d_in[15];
    const float* ln_m_b = (const float*)d_in[16];
    const float* W1 = (const float*)d_in[17];
    const float* b1 = (const float*)d_in[18];
    const float* W2 = (const float*)d_in[19];
    const float* b2 = (const float*)d_in[20];

    char* p = (char*)d_ws;
    auto alloc = [&](size_t bytes) { char* r = p; p += (bytes + 255) & ~(size_t)255; return r; };
    unsigned short* xln = (unsigned short*)alloc(131072ull * 512 * 2);
    unsigned short* wt  = (unsigned short*)alloc(1024ull * 512 * 2);
    unsigned short* kbf = (unsigned short*)alloc(32ull * 4096 * 512 * 2);
    unsigned short* vbf = (unsigned short*)alloc(32ull * 4096 * 512 * 2);
    unsigned short* WqT   = (unsigned short*)alloc(512ull * 512 * 2);
    unsigned short* Wih_b = (unsigned short*)alloc(1536ull * 512 * 2);
    unsigned short* Whh_b = (unsigned short*)alloc(1536ull * 512 * 2);
    unsigned short* W1T   = (unsigned short*)alloc(2048ull * 512 * 2);
    unsigned short* W2T   = (unsigned short*)alloc(512ull * 2048 * 2);
    unsigned short* slq  = (unsigned short*)alloc(384ull * 512 * 2);
    unsigned short* mln  = (unsigned short*)alloc(384ull * 512 * 2);
    unsigned short* upd  = (unsigned short*)alloc(384ull * 512 * 2);
    unsigned short* slbf = (unsigned short*)alloc(384ull * 512 * 2);
    unsigned short* h1   = (unsigned short*)alloc(384ull * 2048 * 2);
    float* q_    = (float*)alloc(384ull * 512 * 4);
    float* slots = (float*)alloc(384ull * 512 * 4);
    float* gi    = (float*)alloc(384ull * 1536 * 4);
    float* gh    = (float*)alloc(384ull * 1536 * 4);
    float* Up    = (float*)alloc((size_t)32 * NCHUNK * 11 * 512 * 4);
    float* rsp   = (float*)alloc((size_t)32 * NCHUNK * 11 * 4);

    // ---- one-time prep ----
    ln512_kernel<true><<<dim3(32768), 256, 0, stream>>>(inputs, ln_in_g, ln_in_b, xln, 131072, 131072, 1.0f);
    prep_wt<<<dim3(2048), 256, 0, stream>>>(Wk, Wv, wt);
    transpose_bf<<<dim3(16, 16), 256, 0, stream>>>(Wq, WqT, 512, 512);
    conv_bf<<<dim3(3072), 256, 0, stream>>>(W_ih, Wih_b, 1536 * 512);
    conv_bf<<<dim3(3072), 256, 0, stream>>>(W_hh, Whh_b, 1536 * 512);
    transpose_bf<<<dim3(64, 16), 256, 0, stream>>>(W1, W1T, 512, 2048);
    transpose_bf<<<dim3(16, 64), 256, 0, stream>>>(W2, W2T, 2048, 512);
    kv_gemm<<<dim3(8192), 256, 0, stream>>>(xln, wt, bk, bv, kbf, vbf);
    hipMemcpyAsync(slots, slots_in, 352ull * 512 * 4, hipMemcpyDeviceToDevice, stream);
    conv_bf_rows<<<dim3(768), 256, 0, stream>>>(slots_in, slbf, 384, 352);

    const float qscale = 0.044194173824159216f;  // 1/sqrt(512)
    for (int it = 0; it < 3; ++it) {
        ln512_kernel<true><<<dim3(96), 256, 0, stream>>>(slots, ln_q_g, ln_q_b, slq, 384, 352, qscale);
        hgemm<false, false, 0><<<dim3(8, 6), 256, 0, stream>>>(slq, WqT, nullptr, q_, nullptr, 512, 512);
        attn_kernel<<<dim3(NCHUNK, 32), 256, 0, stream>>>(q_, kbf, vbf, Up, rsp);
        attn_reduce<<<dim3(384), 256, 0, stream>>>(Up, rsp, upd);
        hgemm<true, false, 0><<<dim3(24, 6), 256, 0, stream>>>(upd, Wih_b, b_ih, gi, nullptr, 1536, 512);
        hgemm<true, false, 0><<<dim3(24, 6), 256, 0, stream>>>(slbf, Whh_b, b_hh, gh, nullptr, 1536, 512);
        gru_kernel<<<dim3(768), 256, 0, stream>>>(gi, gh, slots, slots, slbf);
        ln512_kernel<true><<<dim3(96), 256, 0, stream>>>(slots, ln_m_g, ln_m_b, mln, 384, 352, 1.0f);
        hgemm<true, true, 1><<<dim3(32, 6), 256, 0, stream>>>(mln, W1T, b1, nullptr, h1, 2048, 512);
        hgemm<true, false, 2><<<dim3(8, 6), 256, 0, stream>>>(h1, W2T, b2, slots, slbf, 512, 2048);
    }
    hipMemcpyAsync(d_out, slots, (size_t)out_size * 4, hipMemcpyDeviceToDevice, stream);
}